// Round 1
// baseline (304.893 us; speedup 1.0000x reference)
//
#include <hip/hip_runtime.h>

// Mamba block fused pipeline, MI355X gfx950.
// B=1, L=2048, D_MODEL=1024, D_INNER=2048, D_CONV=4, DT_RANK=64, D_STATE=16.
//
// Pipeline:
//  prep: cast x->bf16; transpose-cast weights to B^T (N,K) bf16 layouts
//  G1: xres(2048x4096) = x @ in_proj_w + b         [bf16 MFMA]
//  conv_silu: u = silu(depthwise_conv(xin)+cb)     [fp32, also emits bf16 u]
//  G3: dbc(2048x128) = u @ x_proj_w (N padded 96->128, split-K=4, atomicAdd)
//  G5: delta = softplus(dt @ dt_proj_w + b)        [bf16 MFMA, fused epilogue]
//  scan: chunked 2-pass diagonal linear recurrence (32 chunks x 64 steps),
//        pass2 fuses y = (scan + u*D)*silu(res) and bf16 cast
//  G2: out = yg @ out_proj_w + b                   [bf16 MFMA]

#define L_SEQ 2048
#define DMODEL 1024
#define DINNER 2048
#define NSTATE 16
#define DTRANK 64
#define NPROJ_PAD 128
#define NCHUNK 32
#define TCH 64  // L_SEQ / NCHUNK

typedef __attribute__((ext_vector_type(8))) short short8;
typedef __attribute__((ext_vector_type(4))) float f32x4;

__device__ __forceinline__ unsigned short f2bf(float f) {
  unsigned int u = __float_as_uint(f);
  u += 0x7FFFu + ((u >> 16) & 1u);  // round-to-nearest-even
  return (unsigned short)(u >> 16);
}

__device__ __forceinline__ void gload16(const void* g, void* l) {
  // async global->LDS, 16B per lane; LDS dest = base + lane*16
  __builtin_amdgcn_global_load_lds((const __attribute__((address_space(1))) void*)g,
                                   (__attribute__((address_space(3))) void*)l, 16, 0, 0);
}

// ---------------- elementwise / prep kernels ----------------

__global__ void cast_bf16_kernel(const float* __restrict__ in, unsigned short* __restrict__ out,
                                 int n) {
  int id = blockIdx.x * 256 + threadIdx.x;
  if (id < n) out[id] = f2bf(in[id]);
}

// dt slice (cols 0..63 of dbc row stride 128) -> contiguous bf16 (2048x64)
__global__ void cast_dt_kernel(const float* __restrict__ dbc, unsigned short* __restrict__ dtb) {
  int id = blockIdx.x * 256 + threadIdx.x;  // 2048*64
  int t = id >> 6, k = id & 63;
  dtb[id] = f2bf(dbc[t * NPROJ_PAD + k]);
}

// in (R x C fp32) -> out (C x R bf16)
__global__ void transpose_cast_kernel(const float* __restrict__ in,
                                      unsigned short* __restrict__ out, int R, int C) {
  __shared__ float tile[32][33];
  const int c0 = blockIdx.x * 32, r0 = blockIdx.y * 32;
  const int tx = threadIdx.x, ty = threadIdx.y;  // block (32,8)
  for (int y = ty; y < 32; y += 8) tile[y][tx] = in[(size_t)(r0 + y) * C + c0 + tx];
  __syncthreads();
  for (int y = ty; y < 32; y += 8) out[(size_t)(c0 + y) * R + r0 + tx] = f2bf(tile[tx][y]);
}

// depthwise causal conv (4 taps) + silu; u fp32 for scan, bf16 for GEMM3
__global__ void conv_silu_kernel(const float* __restrict__ xres, const float* __restrict__ cw,
                                 const float* __restrict__ cb, float* __restrict__ u,
                                 unsigned short* __restrict__ ub) {
  const int id = blockIdx.x * 256 + threadIdx.x;  // over 2048*2048
  const int t = id >> 11;
  const int d = id & (DINNER - 1);
  float acc = cb[d];
#pragma unroll
  for (int j = 0; j < 4; j++) {
    int tt = t - 3 + j;
    if (tt >= 0) acc += xres[(size_t)tt * (2 * DINNER) + d] * cw[j * DINNER + d];
  }
  float s = acc / (1.f + __expf(-acc));  // silu
  u[id] = s;
  ub[id] = f2bf(s);
}

// ---------------- bf16 MFMA GEMM: C[M,N] = A[M,K] @ Bt[N,K]^T ----------------
// 128x128 tile, BK=32, 4 waves each 64x64 of 16x16x32 MFMA frags.
// EPI: 0 = store acc+bias (bias may be null), 1 = store softplus(acc+bias),
//      2 = atomicAdd(C, acc) for split-K (grid.z = K/KS splits).
template <int EPI>
__global__ void gemm_bf16_128(const unsigned short* __restrict__ A,
                              const unsigned short* __restrict__ Bt, float* __restrict__ C,
                              const float* __restrict__ bias, int M, int N, int K, int KS) {
  __shared__ __align__(16) unsigned short lA[128 * 32];
  __shared__ __align__(16) unsigned short lB[128 * 32];
  const int tid = threadIdx.x;
  const int w = tid >> 6;
  const int lane = tid & 63;
  const int m0 = blockIdx.x * 128;
  const int n0 = blockIdx.y * 128;
  const int kbase = blockIdx.z * KS;
  const int lr = lane >> 2;       // row within 16-row group the lane stages
  const int lc = (lane & 3) * 8;  // k-offset (elements) the lane stages
  const int wm = (w & 1) * 64;
  const int wn = (w >> 1) * 64;
  const int ml = lane & 15;
  const int quad = lane >> 4;

  f32x4 acc[4][4];
#pragma unroll
  for (int i = 0; i < 4; i++)
#pragma unroll
    for (int j = 0; j < 4; j++) acc[i][j] = (f32x4){0.f, 0.f, 0.f, 0.f};

  const unsigned short* Ag = A + (size_t)m0 * K + kbase;
  const unsigned short* Bg = Bt + (size_t)n0 * K + kbase;

  for (int kk = 0; kk < KS; kk += 32) {
    // stage A,B tiles (128x32 bf16 each, rows contiguous 64B)
    gload16(Ag + (size_t)(w * 16 + lr) * K + kk + lc, &lA[(w * 16) * 32]);
    gload16(Ag + (size_t)(64 + w * 16 + lr) * K + kk + lc, &lA[(64 + w * 16) * 32]);
    gload16(Bg + (size_t)(w * 16 + lr) * K + kk + lc, &lB[(w * 16) * 32]);
    gload16(Bg + (size_t)(64 + w * 16 + lr) * K + kk + lc, &lB[(64 + w * 16) * 32]);
    __syncthreads();

    short8 af[4], bfr[4];
#pragma unroll
    for (int i = 0; i < 4; i++)
      af[i] = *(const short8*)&lA[(wm + i * 16 + ml) * 32 + quad * 8];
#pragma unroll
    for (int j = 0; j < 4; j++)
      bfr[j] = *(const short8*)&lB[(wn + j * 16 + ml) * 32 + quad * 8];
#pragma unroll
    for (int i = 0; i < 4; i++)
#pragma unroll
      for (int j = 0; j < 4; j++)
        acc[i][j] = __builtin_amdgcn_mfma_f32_16x16x32_bf16(af[i], bfr[j], acc[i][j], 0, 0, 0);
    __syncthreads();
  }

  // epilogue: C/D layout col = lane&15, row = quad*4 + r
#pragma unroll
  for (int i = 0; i < 4; i++) {
#pragma unroll
    for (int j = 0; j < 4; j++) {
      const int col = n0 + wn + j * 16 + ml;
      float bv = 0.f;
      if (EPI != 2 && bias != nullptr) bv = bias[col];
#pragma unroll
      for (int r = 0; r < 4; r++) {
        const int row = m0 + wm + i * 16 + quad * 4 + r;
        float v = acc[i][j][r];
        if (EPI == 2) {
          atomicAdd(&C[(size_t)row * N + col], v);
        } else {
          v += bv;
          if (EPI == 1) v = (v > 15.f) ? v : __logf(1.f + __expf(v));
          C[(size_t)row * N + col] = v;
        }
      }
    }
  }
}

// ---------------- selective scan (chunked 2-pass) ----------------
// Thread = one channel d within one chunk; 16 states in registers.

__global__ void scan1_kernel(const float* __restrict__ delta, const float* __restrict__ u,
                             const float* __restrict__ dbc, const float* __restrict__ A_log,
                             float* __restrict__ P, float* __restrict__ Hz) {
  __shared__ float Bs[TCH][NSTATE];
  const int d = blockIdx.x * 256 + threadIdx.x;
  const int c = blockIdx.y;
  for (int idx = threadIdx.x; idx < TCH * NSTATE; idx += 256) {
    int t = idx >> 4, n = idx & 15;
    Bs[t][n] = dbc[(size_t)(c * TCH + t) * NPROJ_PAD + DTRANK + n];
  }
  float Ad[16], h[16], p[16];
#pragma unroll
  for (int n = 0; n < 16; n++) {
    Ad[n] = -__expf(A_log[d * 16 + n]);
    h[n] = 0.f;
    p[n] = 1.f;
  }
  __syncthreads();
  for (int t = 0; t < TCH; t++) {
    const int tt = c * TCH + t;
    float dl = delta[(size_t)tt * DINNER + d];
    float uu = u[(size_t)tt * DINNER + d];
    float du = dl * uu;
#pragma unroll
    for (int n = 0; n < 16; n++) {
      float dA = __expf(dl * Ad[n]);
      p[n] *= dA;
      h[n] = dA * h[n] + du * Bs[t][n];
    }
  }
#pragma unroll
  for (int n = 0; n < 16; n++) {
    P[(size_t)(c * 16 + n) * DINNER + d] = p[n];
    Hz[(size_t)(c * 16 + n) * DINNER + d] = h[n];
  }
}

__global__ void scan_carry_kernel(const float* __restrict__ P, const float* __restrict__ Hz,
                                  float* __restrict__ H0) {
  const int id = blockIdx.x * 256 + threadIdx.x;  // 16*2048 (n,d) pairs
  float h = 0.f;
#pragma unroll 4
  for (int c = 0; c < NCHUNK; c++) {
    H0[c * (NSTATE * DINNER) + id] = h;
    h = P[c * (NSTATE * DINNER) + id] * h + Hz[c * (NSTATE * DINNER) + id];
  }
}

__global__ void scan2_kernel(const float* __restrict__ delta, const float* __restrict__ u,
                             const float* __restrict__ dbc, const float* __restrict__ A_log,
                             const float* __restrict__ Dv, const float* __restrict__ xres,
                             const float* __restrict__ H0, unsigned short* __restrict__ ygb) {
  __shared__ float Bs[TCH][NSTATE];
  __shared__ float Cs[TCH][NSTATE];
  const int d = blockIdx.x * 256 + threadIdx.x;
  const int c = blockIdx.y;
  for (int idx = threadIdx.x; idx < TCH * 2 * NSTATE; idx += 256) {
    int t = idx >> 5, q = idx & 31;
    float v = dbc[(size_t)(c * TCH + t) * NPROJ_PAD + DTRANK + q];
    if (q < 16) Bs[t][q] = v;
    else Cs[t][q - 16] = v;
  }
  float Ad[16], h[16];
#pragma unroll
  for (int n = 0; n < 16; n++) {
    Ad[n] = -__expf(A_log[d * 16 + n]);
    h[n] = H0[(size_t)(c * 16 + n) * DINNER + d];
  }
  const float Dd = Dv[d];
  __syncthreads();
  for (int t = 0; t < TCH; t++) {
    const int tt = c * TCH + t;
    float dl = delta[(size_t)tt * DINNER + d];
    float uu = u[(size_t)tt * DINNER + d];
    float du = dl * uu;
    float y0 = 0.f, y1 = 0.f;
#pragma unroll
    for (int n = 0; n < 16; n++) {
      float dA = __expf(dl * Ad[n]);
      h[n] = dA * h[n] + du * Bs[t][n];
      if (n & 1) y1 += h[n] * Cs[t][n];
      else y0 += h[n] * Cs[t][n];
    }
    float r = xres[(size_t)tt * (2 * DINNER) + DINNER + d];
    float sil = r / (1.f + __expf(-r));
    float yg = (y0 + y1 + uu * Dd) * sil;
    ygb[(size_t)tt * DINNER + d] = f2bf(yg);
  }
}

// ---------------- launch ----------------

extern "C" void kernel_launch(void* const* d_in, const int* in_sizes, int n_in, void* d_out,
                              int out_size, void* d_ws, size_t ws_size, hipStream_t stream) {
  const float* x = (const float*)d_in[0];
  const float* in_proj_w = (const float*)d_in[1];
  const float* in_proj_b = (const float*)d_in[2];
  const float* conv_w = (const float*)d_in[3];
  const float* conv_b = (const float*)d_in[4];
  const float* x_proj_w = (const float*)d_in[5];
  const float* dt_proj_w = (const float*)d_in[6];
  const float* dt_proj_b = (const float*)d_in[7];
  const float* A_log = (const float*)d_in[8];
  const float* Dvec = (const float*)d_in[9];
  const float* out_proj_w = (const float*)d_in[10];
  const float* out_proj_b = (const float*)d_in[11];
  float* out = (float*)d_out;
  char* ws = (char*)d_ws;

  // workspace layout (bytes), all 256-aligned; total ~115 MiB
  const size_t XB = 0;                       // 2048x1024 bf16        4 MiB
  const size_t W1T = XB + 4194304;           // 4096x1024 bf16        8 MiB
  const size_t XRES = W1T + 8388608;         // 2048x4096 fp32       32 MiB
  const size_t U = XRES + 33554432;          // 2048x2048 fp32       16 MiB
  const size_t UB = U + 16777216;            // 2048x2048 bf16        8 MiB
  const size_t W3T = UB + 8388608;           // 128x2048 bf16       0.5 MiB
  const size_t DBC = W3T + 524288;           // 2048x128 fp32         1 MiB
  const size_t DTB = DBC + 1048576;          // 2048x64 bf16       0.25 MiB
  const size_t W4T = DTB + 262144;           // 2048x64 bf16       0.25 MiB
  const size_t DELTA = W4T + 262144;         // 2048x2048 fp32       16 MiB
  const size_t PBUF = DELTA + 16777216;      // 32x16x2048 fp32       4 MiB
  const size_t HZB = PBUF + 4194304;         //                       4 MiB
  const size_t H0B = HZB + 4194304;          //                       4 MiB
  const size_t YGB = H0B + 4194304;          // 2048x2048 bf16        8 MiB
  const size_t W5T = YGB + 8388608;          // 1024x2048 bf16        4 MiB
  (void)ws_size; (void)in_sizes; (void)n_in; (void)out_size;

  // zero pad rows of w3t and the split-K accumulator
  hipMemsetAsync(ws + W3T, 0, NPROJ_PAD * DINNER * 2, stream);
  hipMemsetAsync(ws + DBC, 0, (size_t)L_SEQ * NPROJ_PAD * 4, stream);

  // prep casts
  cast_bf16_kernel<<<(L_SEQ * DMODEL) / 256, 256, 0, stream>>>(x, (unsigned short*)(ws + XB),
                                                               L_SEQ * DMODEL);
  transpose_cast_kernel<<<dim3(4096 / 32, 1024 / 32), dim3(32, 8), 0, stream>>>(
      in_proj_w, (unsigned short*)(ws + W1T), 1024, 4096);
  transpose_cast_kernel<<<dim3(96 / 32, 2048 / 32), dim3(32, 8), 0, stream>>>(
      x_proj_w, (unsigned short*)(ws + W3T), 2048, 96);
  transpose_cast_kernel<<<dim3(2048 / 32, 64 / 32), dim3(32, 8), 0, stream>>>(
      dt_proj_w, (unsigned short*)(ws + W4T), 64, 2048);
  transpose_cast_kernel<<<dim3(1024 / 32, 2048 / 32), dim3(32, 8), 0, stream>>>(
      out_proj_w, (unsigned short*)(ws + W5T), 2048, 1024);

  // G1: xres = x @ in_proj_w + b   (M=2048,N=4096,K=1024)
  gemm_bf16_128<0><<<dim3(16, 32, 1), 256, 0, stream>>>(
      (const unsigned short*)(ws + XB), (const unsigned short*)(ws + W1T), (float*)(ws + XRES),
      in_proj_b, 2048, 4096, 1024, 1024);

  // conv + silu
  conv_silu_kernel<<<(L_SEQ * DINNER) / 256, 256, 0, stream>>>(
      (const float*)(ws + XRES), conv_w, conv_b, (float*)(ws + U), (unsigned short*)(ws + UB));

  // G3: dbc += u @ x_proj_w  (M=2048,N=128,K=2048, split-K=4 w/ atomics)
  gemm_bf16_128<2><<<dim3(16, 1, 4), 256, 0, stream>>>(
      (const unsigned short*)(ws + UB), (const unsigned short*)(ws + W3T), (float*)(ws + DBC),
      nullptr, 2048, NPROJ_PAD, 2048, 512);

  cast_dt_kernel<<<(L_SEQ * DTRANK) / 256, 256, 0, stream>>>((const float*)(ws + DBC),
                                                             (unsigned short*)(ws + DTB));

  // G5: delta = softplus(dt @ dt_proj_w + b)  (M=2048,N=2048,K=64)
  gemm_bf16_128<1><<<dim3(16, 16, 1), 256, 0, stream>>>(
      (const unsigned short*)(ws + DTB), (const unsigned short*)(ws + W4T), (float*)(ws + DELTA),
      dt_proj_b, 2048, 2048, 64, 64);

  // selective scan
  scan1_kernel<<<dim3(DINNER / 256, NCHUNK), 256, 0, stream>>>(
      (const float*)(ws + DELTA), (const float*)(ws + U), (const float*)(ws + DBC), A_log,
      (float*)(ws + PBUF), (float*)(ws + HZB));
  scan_carry_kernel<<<(NSTATE * DINNER) / 256, 256, 0, stream>>>(
      (const float*)(ws + PBUF), (const float*)(ws + HZB), (float*)(ws + H0B));
  scan2_kernel<<<dim3(DINNER / 256, NCHUNK), 256, 0, stream>>>(
      (const float*)(ws + DELTA), (const float*)(ws + U), (const float*)(ws + DBC), A_log, Dvec,
      (const float*)(ws + XRES), (const float*)(ws + H0B), (unsigned short*)(ws + YGB));

  // G2: out = yg @ out_proj_w + b  (M=2048,N=1024,K=2048)
  gemm_bf16_128<0><<<dim3(16, 8, 1), 256, 0, stream>>>(
      (const unsigned short*)(ws + YGB), (const unsigned short*)(ws + W5T), out, out_proj_b, 2048,
      1024, 2048, 2048);
}